// Round 8
// baseline (1173.317 us; speedup 1.0000x reference)
//
#include <hip/hip_runtime.h>

#define TAILB 12.0f

typedef __attribute__((ext_vector_type(8))) short short8;   // 8 bf16 (4 VGPRs)
typedef __attribute__((ext_vector_type(4))) float f32x4;    // MFMA C/D frag

__device__ __forceinline__ unsigned short f2bf(float f) {
    union { float f; unsigned int u; } v; v.f = f;
    return (unsigned short)((v.u + 0x7FFFu + ((v.u >> 16) & 1u)) >> 16);  // RNE
}
__device__ __forceinline__ float bf2f(unsigned short s) {
    union { unsigned int u; float f; } v; v.u = ((unsigned int)s) << 16;
    return v.f;
}
// 3-term RNE split: v = b0 + b1 + b2 + eps, |eps| <= 2^-27 |v|
__device__ __forceinline__ void split3(float v, unsigned short& o0,
                                       unsigned short& o1, unsigned short& o2) {
    unsigned short s0 = f2bf(v);
    float r1 = v - bf2f(s0);
    unsigned short s1 = f2bf(r1);
    float r2 = r1 - bf2f(s1);
    o0 = s0; o1 = s1; o2 = f2bf(r2);
}

__device__ __forceinline__ float softplus_f(float z) {
    return (z > 15.f) ? z : log1pf(__expf(z));
}

// ---- prep: 3-term bf16 planes for W2 ([4][128][128]) and W3 ([4][48][128] padded),
//      plus w1p float4 pack {W1[k][0..2], b1[k]}.
// ws: W2b0 @0, W2b1 @131072, W2b2 @262144 (131072 B each)
//     W3b0 @393216, W3b1 @442368, W3b2 @491520 (49152 B each)
//     w1p  @540672 (8192 B)  -> total 548864 B
__global__ __launch_bounds__(256)
void prep_v8(const float* __restrict__ W1, const float* __restrict__ b1,
             const float* __restrict__ W2, const float* __restrict__ W3,
             unsigned short* __restrict__ W2b0, unsigned short* __restrict__ W2b1,
             unsigned short* __restrict__ W2b2,
             unsigned short* __restrict__ W3b0, unsigned short* __restrict__ W3b1,
             unsigned short* __restrict__ W3b2, float4* __restrict__ w1p)
{
    int id = blockIdx.x * 256 + threadIdx.x;
    if (id < 65536) {
        unsigned short a, b, c;
        split3(W2[id], a, b, c);
        W2b0[id] = a; W2b1[id] = b; W2b2[id] = c;
    } else if (id < 90112) {
        int t = id - 65536;
        int l = t / 6144, rem = t % 6144;
        int r = rem / 128, k = rem % 128;
        float v = (r < 46) ? W3[l * 5888 + r * 128 + k] : 0.f;
        unsigned short a, b, c;
        split3(v, a, b, c);
        W3b0[t] = a; W3b1[t] = b; W3b2[t] = c;
    } else if (id < 90624) {
        int t = id - 90112;
        int l = t >> 7, k = t & 127;
        float4 v;
        v.x = W1[l * 384 + k * 3 + 0];
        v.y = W1[l * 384 + k * 3 + 1];
        v.z = W1[l * 384 + k * 3 + 2];
        v.w = b1[l * 128 + k];
        w1p[t] = v;
    }
}

#define MFMA __builtin_amdgcn_mfma_f32_16x16x32_bf16

// 64 samples/block, 4 waves x 16 samples (round-2 verified fragment layout).
// GEMMs run as split-bf16 MFMA: 6 products {A0B0,A0B1,A1B0,A0B2,A1B1,A2B0},
// total rel err ~1.5e-8 < fp32 eps -> numerically equivalent to fp32 GEMM.
// h2 stays fp32 in LDS (split on read). smem unions h2buf[64][132] with
// pbuf[48][65]. 4 barriers/layer.
__global__ __launch_bounds__(256, 4)
void rqs_v8(const float* __restrict__ inp, const float* __restrict__ cond,
            const unsigned short* __restrict__ W2b0, const unsigned short* __restrict__ W2b1,
            const unsigned short* __restrict__ W2b2,
            const unsigned short* __restrict__ W3b0, const unsigned short* __restrict__ W3b1,
            const unsigned short* __restrict__ W3b2,
            const float4* __restrict__ w1p,
            const float* __restrict__ b2, const float* __restrict__ b3,
            float* __restrict__ out, int B)
{
    __shared__ __align__(16) float smem[64 * 132];  // h2buf [s][132] | pbuf [48][65]
    __shared__ float xbuf[64][5];
    __shared__ float ladbuf[2][64];
    __shared__ float ldacc[64];

    float* h2buf = smem;
    float* pbuf  = smem;

    const int tid  = threadIdx.x;
    const int base = blockIdx.x * 64;
    const int wv   = tid >> 6;
    const int ln   = tid & 63;
    const int sm   = ln & 15;        // M/N index within 16-tile (W-row or sample)
    const int qd   = ln >> 4;        // quad: k = 8*qd + j (+32*cs)
    const int srow = wv * 16 + sm;   // this lane's sample (0..63)

    if (tid < 64) {
        float4 xi = reinterpret_cast<const float4*>(inp)[base + tid];
        xbuf[tid][0] = xi.x; xbuf[tid][1] = xi.y;
        xbuf[tid][2] = xi.z; xbuf[tid][3] = xi.w;
        xbuf[tid][4] = cond[base + tid];
        ldacc[tid] = 0.f;
    }
    __syncthreads();

    #pragma unroll 1
    for (int l = 0; l < 4; ++l) {
        int mi0, mi1, ii0, ii1;
        switch (l) {
            case 0:  mi0 = 0; mi1 = 2; ii0 = 1; ii1 = 3; break;
            case 1:  mi0 = 1; mi1 = 3; ii0 = 0; ii1 = 2; break;
            case 2:  mi0 = 0; mi1 = 1; ii0 = 2; ii1 = 3; break;
            default: mi0 = 2; mi1 = 3; ii0 = 0; ii1 = 1; break;
        }

        // ---- h1 B-frags (3-term split): lane holds h1[srow][k=32cs+8qd+j] ----
        float m0 = xbuf[srow][mi0], m1 = xbuf[srow][mi1], cc = xbuf[srow][4];
        const float4* w1l = w1p + l * 128;
        short8 hf0[4], hf1[4], hf2[4];
        #pragma unroll
        for (int cs = 0; cs < 4; ++cs) {
            #pragma unroll
            for (int j = 0; j < 8; ++j) {
                int k = 32 * cs + 8 * qd + j;
                float4 wv4 = w1l[k];
                float v = fmaf(wv4.x, m0, fmaf(wv4.y, m1, fmaf(wv4.z, cc, wv4.w)));
                v = fmaxf(v, 0.f);
                unsigned short a, b, c;
                split3(v, a, b, c);
                hf0[cs][j] = (short)a; hf1[cs][j] = (short)b; hf2[cs][j] = (short)c;
            }
        }

        // ---- GEMM2: h2[n][s] via 6-product split MFMA ----
        const float* b2l = b2 + l * 128;
        #pragma unroll 1
        for (int t = 0; t < 8; ++t) {
            f32x4 acc = {0.f, 0.f, 0.f, 0.f};
            #pragma unroll
            for (int cs = 0; cs < 4; ++cs) {
                int off = l * 16384 + (16 * t + sm) * 128 + 32 * cs + 8 * qd;
                short8 A0 = *reinterpret_cast<const short8*>(W2b0 + off);
                short8 A1 = *reinterpret_cast<const short8*>(W2b1 + off);
                short8 A2 = *reinterpret_cast<const short8*>(W2b2 + off);
                acc = MFMA(A0, hf0[cs], acc, 0, 0, 0);
                acc = MFMA(A0, hf1[cs], acc, 0, 0, 0);
                acc = MFMA(A1, hf0[cs], acc, 0, 0, 0);
                acc = MFMA(A0, hf2[cs], acc, 0, 0, 0);
                acc = MFMA(A1, hf1[cs], acc, 0, 0, 0);
                acc = MFMA(A2, hf0[cs], acc, 0, 0, 0);
            }
            // lane holds h2[n=16t+4qd+r][sample=srow]
            float4 bias = *reinterpret_cast<const float4*>(b2l + 16 * t + 4 * qd);
            float4 hv;
            hv.x = fmaxf(acc[0] + bias.x, 0.f);
            hv.y = fmaxf(acc[1] + bias.y, 0.f);
            hv.z = fmaxf(acc[2] + bias.z, 0.f);
            hv.w = fmaxf(acc[3] + bias.w, 0.f);
            *reinterpret_cast<float4*>(&h2buf[srow * 132 + 16 * t + 4 * qd]) = hv;
        }
        __syncthreads();   // b1: all h2 stores visible

        // ---- split h2 on read -> GEMM3 B-frags ----
        short8 gf0[4], gf1[4], gf2[4];
        #pragma unroll
        for (int cs = 0; cs < 4; ++cs) {
            float4 u0 = *reinterpret_cast<const float4*>(&h2buf[srow * 132 + 32 * cs + 8 * qd]);
            float4 u1 = *reinterpret_cast<const float4*>(&h2buf[srow * 132 + 32 * cs + 8 * qd + 4]);
            float uv[8] = {u0.x, u0.y, u0.z, u0.w, u1.x, u1.y, u1.z, u1.w};
            #pragma unroll
            for (int j = 0; j < 8; ++j) {
                unsigned short a, b, c;
                split3(uv[j], a, b, c);
                gf0[cs][j] = (short)a; gf1[cs][j] = (short)b; gf2[cs][j] = (short)c;
            }
        }
        __syncthreads();   // b2: all h2 reads done -> pbuf overlay safe

        // ---- GEMM3: params[p][s] ----
        #pragma unroll 1
        for (int t3 = 0; t3 < 3; ++t3) {
            f32x4 acc = {0.f, 0.f, 0.f, 0.f};
            #pragma unroll
            for (int cs = 0; cs < 4; ++cs) {
                int off = l * 6144 + (16 * t3 + sm) * 128 + 32 * cs + 8 * qd;
                short8 A0 = *reinterpret_cast<const short8*>(W3b0 + off);
                short8 A1 = *reinterpret_cast<const short8*>(W3b1 + off);
                short8 A2 = *reinterpret_cast<const short8*>(W3b2 + off);
                acc = MFMA(A0, gf0[cs], acc, 0, 0, 0);
                acc = MFMA(A0, gf1[cs], acc, 0, 0, 0);
                acc = MFMA(A1, gf0[cs], acc, 0, 0, 0);
                acc = MFMA(A0, gf2[cs], acc, 0, 0, 0);
                acc = MFMA(A1, gf1[cs], acc, 0, 0, 0);
                acc = MFMA(A2, gf0[cs], acc, 0, 0, 0);
            }
            // lane holds params[p=16t3+4qd+r][sample=srow]
            #pragma unroll
            for (int r = 0; r < 4; ++r)
                pbuf[(16 * t3 + 4 * qd + r) * 65 + srow] = acc[r];
        }
        __syncthreads();   // b3: params visible

        // ---- spline: thread (f = tid>>6, s = tid&63) ----
        if (tid < 128) {
            int f = tid >> 6, s = tid & 63;
            const float* b3l = b3 + l * 46;
            float pr[23];
            #pragma unroll
            for (int i = 0; i < 23; ++i)
                pr[i] = pbuf[(2 * i + f) * 65 + s] + b3l[2 * i + f];

            float xin = xbuf[s][f == 0 ? ii0 : ii1];

            float d[9];
            d[0] = 1.f; d[8] = 1.f;
            #pragma unroll
            for (int k = 1; k < 8; ++k) d[k] = 1e-6f + softplus_f(pr[16 + k - 1]);

            bool inside = (xin >= -TAILB) && (xin <= TAILB);
            float xc = fminf(fmaxf(xin, -TAILB), TAILB);

            float mw = pr[0], mh = pr[8];
            #pragma unroll
            for (int k = 1; k < 8; ++k) { mw = fmaxf(mw, pr[k]); mh = fmaxf(mh, pr[8 + k]); }
            float ew[8], eh[8], swm = 0.f, shm = 0.f;
            #pragma unroll
            for (int k = 0; k < 8; ++k) {
                ew[k] = __expf(pr[k] - mw);     swm += ew[k];
                eh[k] = __expf(pr[8 + k] - mh); shm += eh[k];
            }
            const float c1 = 1.f - 8e-6f;
            float isw = c1 / swm, ish = c1 / shm;

            float cum_w = 0.f, cum_h = 0.f;
            float cwk = -TAILB, chk = -TAILB;
            float s_cw = -TAILB, s_w = 2.f * TAILB, s_ch = -TAILB, s_h = 2.f * TAILB;
            float s_d0 = 1.f, s_d1 = d[1];
            #pragma unroll
            for (int k = 0; k < 8; ++k) {
                cum_w += fmaf(ew[k], isw, 1e-6f);
                cum_h += fmaf(eh[k], ish, 1e-6f);
                float cwn = (k == 7) ? TAILB : fmaf(2.f * TAILB, cum_w, -TAILB);
                float chn = (k == 7) ? TAILB : fmaf(2.f * TAILB, cum_h, -TAILB);
                bool ge = (xc >= cwk);
                s_cw = ge ? cwk : s_cw;  s_w = ge ? (cwn - cwk) : s_w;
                s_ch = ge ? chk : s_ch;  s_h = ge ? (chn - chk) : s_h;
                s_d0 = ge ? d[k] : s_d0; s_d1 = ge ? d[k + 1] : s_d1;
                cwk = cwn; chk = chn;
            }

            float th    = (xc - s_cw) / s_w;
            float delta = s_h / s_w;
            float omt   = 1.f - th;
            float tomt  = th * omt;
            float num   = s_h * fmaf(delta, th * th, s_d0 * tomt);
            float den   = fmaf(s_d0 + s_d1 - 2.f * delta, tomt, delta);
            float y     = s_ch + num / den;
            float dnum  = delta * delta * (s_d1 * th * th + 2.f * delta * tomt + s_d0 * omt * omt);
            float lad   = __logf(dnum) - 2.f * __logf(den);

            xbuf[s][f == 0 ? ii0 : ii1] = inside ? y : xin;
            ladbuf[f][s] = inside ? lad : 0.f;
        }
        __syncthreads();   // b4: spline done (xbuf/ladbuf visible; pbuf reads done)
        if (tid < 64) ldacc[tid] += ladbuf[0][tid] + ladbuf[1][tid];
    } // l

    if (tid < 64) {
        float4 xo;
        xo.x = xbuf[tid][0]; xo.y = xbuf[tid][1];
        xo.z = xbuf[tid][2]; xo.w = xbuf[tid][3];
        reinterpret_cast<float4*>(out)[base + tid] = xo;
        out[(size_t)B * 4 + base + tid] = ldacc[tid];
    }
}

extern "C" void kernel_launch(void* const* d_in, const int* in_sizes, int n_in,
                              void* d_out, int out_size, void* d_ws, size_t ws_size,
                              hipStream_t stream) {
    const float* inp  = (const float*)d_in[0];
    const float* cond = (const float*)d_in[1];
    const float* W1   = (const float*)d_in[2];
    const float* b1   = (const float*)d_in[3];
    const float* W2   = (const float*)d_in[4];
    const float* b2   = (const float*)d_in[5];
    const float* W3   = (const float*)d_in[6];
    const float* b3   = (const float*)d_in[7];
    float* out = (float*)d_out;
    int B = in_sizes[0] / 4;

    char* ws = (char*)d_ws;
    unsigned short* W2b0 = (unsigned short*)(ws);
    unsigned short* W2b1 = (unsigned short*)(ws + 131072);
    unsigned short* W2b2 = (unsigned short*)(ws + 262144);
    unsigned short* W3b0 = (unsigned short*)(ws + 393216);
    unsigned short* W3b1 = (unsigned short*)(ws + 442368);
    unsigned short* W3b2 = (unsigned short*)(ws + 491520);
    float4*         w1p  = (float4*)(ws + 540672);

    hipLaunchKernelGGL(prep_v8, dim3(354), dim3(256), 0, stream,
                       W1, b1, W2, W3, W2b0, W2b1, W2b2, W3b0, W3b1, W3b2, w1p);
    hipLaunchKernelGGL(rqs_v8, dim3(B / 64), dim3(256), 0, stream,
                       inp, cond, W2b0, W2b1, W2b2, W3b0, W3b1, W3b2, w1p, b2, b3, out, B);
}

// Round 9
// 388.362 us; speedup vs baseline: 3.0212x; 3.0212x over previous
//
#include <hip/hip_runtime.h>

#define TAILB 12.0f

typedef __attribute__((ext_vector_type(8))) short short8;   // 8 bf16 (4 VGPRs)
typedef __attribute__((ext_vector_type(4))) float f32x4;    // MFMA C/D frag

#define MFMA __builtin_amdgcn_mfma_f32_16x16x32_bf16

__device__ __forceinline__ unsigned int f2bf_rne(float f) {
    union { float f; unsigned int u; } v; v.f = f;
    return (v.u + 0x7FFFu + ((v.u >> 16) & 1u)) >> 16;
}
// RNE 3-term split (prep only; matches v8 weight planes exactly)
__device__ __forceinline__ void split3_rne(float v, unsigned short& o0,
                                           unsigned short& o1, unsigned short& o2) {
    unsigned int s0 = f2bf_rne(v);
    union { unsigned int u; float f; } t0; t0.u = s0 << 16;
    float r1 = v - t0.f;
    unsigned int s1 = f2bf_rne(r1);
    union { unsigned int u; float f; } t1; t1.u = s1 << 16;
    float r2 = r1 - t1.f;
    o0 = (unsigned short)s0; o1 = (unsigned short)s1; o2 = (unsigned short)f2bf_rne(r2);
}

__device__ __forceinline__ float softplus_f(float z) {
    return (z > 15.f) ? z : log1pf(__expf(z));
}

// ---------------- prep: A-fragment-packed 3-plane bf16 weights ----------------
// W2F: frag tile = (l*4+wv)*2+t)*4+cs; elem [(tile*3+p)*512 + ln*8 + j]
//      source W2[l][n=32wv+16t+(ln&15)][k=32cs+8(ln>>4)+j]      (393216 B)
// W3F: tile3 = (l*3+wv)*4+cs; elem [(tile3*3+p)*512 + ln*8 + j]
//      source W3[l][p=16wv+(ln&15)][n=32cs+8(ln>>4)+j], rows 46,47 = 0  (147456 B)
// w1p: [l][k] = {W1[k][0..2], b1[k]}                               (8192 B)
__global__ __launch_bounds__(256)
void prep_v9(const float* __restrict__ W1, const float* __restrict__ b1,
             const float* __restrict__ W2, const float* __restrict__ W3,
             unsigned short* __restrict__ W2F, unsigned short* __restrict__ W3F,
             float4* __restrict__ w1p)
{
    int id = blockIdx.x * 256 + threadIdx.x;
    if (id < 65536) {
        int j = id & 7, ln = (id >> 3) & 63, tile = id >> 9;
        int cs = tile & 3, t = (tile >> 2) & 1, wv = (tile >> 3) & 3, l = tile >> 5;
        int n = 32 * wv + 16 * t + (ln & 15);
        int k = 32 * cs + 8 * (ln >> 4) + j;
        unsigned short a, b, c;
        split3_rne(W2[l * 16384 + n * 128 + k], a, b, c);
        W2F[(tile * 3 + 0) * 512 + ln * 8 + j] = a;
        W2F[(tile * 3 + 1) * 512 + ln * 8 + j] = b;
        W2F[(tile * 3 + 2) * 512 + ln * 8 + j] = c;
    } else if (id < 90112) {
        int t2 = id - 65536;
        int j = t2 & 7, ln = (t2 >> 3) & 63, tile3 = t2 >> 9;
        int cs = tile3 & 3, q = tile3 >> 2;
        int wv = q % 3, l = q / 3;
        int p = 16 * wv + (ln & 15);
        int n = 32 * cs + 8 * (ln >> 4) + j;
        float v = (p < 46) ? W3[l * 5888 + p * 128 + n] : 0.f;
        unsigned short a, b, c;
        split3_rne(v, a, b, c);
        W3F[(tile3 * 3 + 0) * 512 + ln * 8 + j] = a;
        W3F[(tile3 * 3 + 1) * 512 + ln * 8 + j] = b;
        W3F[(tile3 * 3 + 2) * 512 + ln * 8 + j] = c;
    } else if (id < 90624) {
        int t = id - 90112;
        int l = t >> 7, k = t & 127;
        float4 v;
        v.x = W1[l * 384 + k * 3 + 0];
        v.y = W1[l * 384 + k * 3 + 1];
        v.z = W1[l * 384 + k * 3 + 2];
        v.w = b1[l * 128 + k];
        w1p[t] = v;
    }
}

// Activation planes in LDS: 3 planes x 64 rows(samples) x 136 bf16 (272 B rows,
// 16B-aligned). 16B pair-group pg stored at (pg ^ ((row>>3)&7))*16 -> b128 reads
// 2-way (free), phase-1 b64 writes conflict-free, compute stays wave-uniform.
__device__ __forceinline__ short8 plane_read(const short* pl, int p, int row,
                                             int cs, int qd) {
    int pg = 4 * cs + qd;
    int key = (row >> 3) & 7;
    return *reinterpret_cast<const short8*>(
        (const char*)pl + p * 17408 + row * 272 + ((pg ^ key) << 4));
}

// 64 samples/block, 4 waves. Wave wv owns n in [32wv,32wv+32) for GEMM2 and
// p-tile 16wv (wv<3) for GEMM3. Split-6 bf16 MFMA == fp32 GEMM numerically
// (v8-verified, absmax 0.5). Activations split once into LDS planes; weights
// ping-pong from L2-resident packed frags.
__global__ __launch_bounds__(256, 3)
void rqs_v9(const float* __restrict__ inp, const float* __restrict__ cond,
            const unsigned short* __restrict__ W2F, const unsigned short* __restrict__ W3F,
            const float4* __restrict__ w1p,
            const float* __restrict__ b2, const float* __restrict__ b3,
            float* __restrict__ out, int B)
{
    __shared__ __align__(16) short planes[3][64][136];   // 52224 B; pbuf/ladb overlay
    __shared__ float xbuf[64][5];

    float* pbuf = (float*)planes;            // [48][65] = 12480 B
    float* ladb = pbuf + 3120;               // [2][64]  = 512 B (within plane 0)
    const short* pl = &planes[0][0][0];

    const int tid  = threadIdx.x;
    const int base = blockIdx.x * 64;
    const int wv   = tid >> 6;
    const int ln   = tid & 63;
    const int sm   = ln & 15;
    const int qd   = ln >> 4;

    if (tid < 64) {
        float4 xi = reinterpret_cast<const float4*>(inp)[base + tid];
        xbuf[tid][0] = xi.x; xbuf[tid][1] = xi.y;
        xbuf[tid][2] = xi.z; xbuf[tid][3] = xi.w;
        xbuf[tid][4] = cond[base + tid];
    }
    float ladreg = 0.f;
    __syncthreads();

    #pragma unroll 1
    for (int l = 0; l < 4; ++l) {
        int mi0, mi1, ii0, ii1;
        switch (l) {
            case 0:  mi0 = 0; mi1 = 2; ii0 = 1; ii1 = 3; break;
            case 1:  mi0 = 1; mi1 = 3; ii0 = 0; ii1 = 2; break;
            case 2:  mi0 = 0; mi1 = 1; ii0 = 2; ii1 = 3; break;
            default: mi0 = 2; mi1 = 3; ii0 = 0; ii1 = 1; break;
        }

        // ---- phase 1: h1 planes; wave wv covers k in [32wv,32wv+32) for its 64 s ----
        {
            int s = tid & 63;
            float m0 = xbuf[s][mi0], m1 = xbuf[s][mi1], cc = xbuf[s][4];
            const float4* w1l = w1p + l * 128;
            int key = (s >> 3) & 7;
            char* rowp = (char*)pl + s * 272;
            #pragma unroll
            for (int g = 0; g < 8; ++g) {
                int k0 = 32 * wv + 4 * g;                  // wave-uniform -> s_loads
                unsigned int q0[4], q1[4], q2[4];
                #pragma unroll
                for (int r = 0; r < 4; ++r) {
                    float4 w4 = w1l[k0 + r];
                    float v = fmaf(w4.x, m0, fmaf(w4.y, m1, fmaf(w4.z, cc, w4.w)));
                    v = fmaxf(v, 0.f);
                    unsigned int u = __float_as_uint(v);
                    q0[r] = u >> 16;                       // trunc bf16 term 0
                    float r1 = v - __uint_as_float(u & 0xFFFF0000u);
                    unsigned int u1 = __float_as_uint(r1);
                    q1[r] = u1 >> 16;                      // trunc term 1
                    float r2 = r1 - __uint_as_float(u1 & 0xFFFF0000u);
                    q2[r] = f2bf_rne(r2);                  // RNE term 2
                }
                int pg = 4 * wv + (g >> 1);
                int boff = ((pg ^ key) << 4) + ((g & 1) << 3);
                uint2 v0 = {q0[0] | (q0[1] << 16), q0[2] | (q0[3] << 16)};
                uint2 v1 = {q1[0] | (q1[1] << 16), q1[2] | (q1[3] << 16)};
                uint2 v2 = {q2[0] | (q2[1] << 16), q2[2] | (q2[3] << 16)};
                *(uint2*)(rowp + boff)         = v0;
                *(uint2*)(rowp + boff + 17408) = v1;
                *(uint2*)(rowp + boff + 34816) = v2;
            }
        }
        __syncthreads();   // B1: h1 planes ready

        // ---- GEMM2: wave wv computes h2 rows [32wv,32wv+32) x 64 samples ----
        f32x4 acc[2][4];
        #pragma unroll
        for (int t = 0; t < 2; ++t)
            #pragma unroll
            for (int st = 0; st < 4; ++st) acc[t][st] = (f32x4){0.f, 0.f, 0.f, 0.f};
        {
            const short8* W2F8 = (const short8*)W2F;
            int tb = (l * 4 + wv) * 2;
            short8 Ac[6], An[6];
            #pragma unroll
            for (int t = 0; t < 2; ++t)
                #pragma unroll
                for (int p = 0; p < 3; ++p)
                    Ac[t * 3 + p] = W2F8[(((tb + t) * 4 + 0) * 3 + p) * 64 + ln];
            #pragma unroll 1
            for (int cs = 0; cs < 4; ++cs) {
                if (cs < 3) {
                    #pragma unroll
                    for (int t = 0; t < 2; ++t)
                        #pragma unroll
                        for (int p = 0; p < 3; ++p)
                            An[t * 3 + p] = W2F8[(((tb + t) * 4 + cs + 1) * 3 + p) * 64 + ln];
                }
                #pragma unroll
                for (int st = 0; st < 4; ++st) {
                    int row = 16 * st + sm;
                    short8 b0 = plane_read(pl, 0, row, cs, qd);
                    short8 b1 = plane_read(pl, 1, row, cs, qd);
                    short8 bb = plane_read(pl, 2, row, cs, qd);
                    #pragma unroll
                    for (int t = 0; t < 2; ++t) {
                        f32x4 a = acc[t][st];
                        a = MFMA(Ac[t * 3 + 0], b0, a, 0, 0, 0);
                        a = MFMA(Ac[t * 3 + 0], b1, a, 0, 0, 0);
                        a = MFMA(Ac[t * 3 + 1], b0, a, 0, 0, 0);
                        a = MFMA(Ac[t * 3 + 0], bb, a, 0, 0, 0);
                        a = MFMA(Ac[t * 3 + 1], b1, a, 0, 0, 0);
                        a = MFMA(Ac[t * 3 + 2], b0, a, 0, 0, 0);
                        acc[t][st] = a;
                    }
                }
                if (cs < 3) {
                    #pragma unroll
                    for (int i = 0; i < 6; ++i) Ac[i] = An[i];
                }
            }
        }
        __syncthreads();   // B2: all h1 reads done -> h2 overwrite safe

        // ---- h2 epilogue: bias+relu, trunc-split, write planes ----
        {
            const float* b2l = b2 + l * 128;
            #pragma unroll
            for (int t = 0; t < 2; ++t) {
                float4 bias = *(const float4*)(b2l + 32 * wv + 16 * t + 4 * qd);
                #pragma unroll
                for (int st = 0; st < 4; ++st) {
                    float hv[4];
                    hv[0] = fmaxf(acc[t][st][0] + bias.x, 0.f);
                    hv[1] = fmaxf(acc[t][st][1] + bias.y, 0.f);
                    hv[2] = fmaxf(acc[t][st][2] + bias.z, 0.f);
                    hv[3] = fmaxf(acc[t][st][3] + bias.w, 0.f);
                    unsigned int q0[4], q1[4], q2[4];
                    #pragma unroll
                    for (int r = 0; r < 4; ++r) {
                        unsigned int u = __float_as_uint(hv[r]);
                        q0[r] = u >> 16;
                        float r1 = hv[r] - __uint_as_float(u & 0xFFFF0000u);
                        unsigned int u1 = __float_as_uint(r1);
                        q1[r] = u1 >> 16;
                        float r2 = r1 - __uint_as_float(u1 & 0xFFFF0000u);
                        q2[r] = f2bf_rne(r2);
                    }
                    int row = 16 * st + sm;
                    int key = (row >> 3) & 7;
                    int pg = 4 * wv + 2 * t + (qd >> 1);
                    int boff = ((pg ^ key) << 4) + ((qd & 1) << 3);
                    char* rp = (char*)pl + row * 272 + boff;
                    uint2 v0 = {q0[0] | (q0[1] << 16), q0[2] | (q0[3] << 16)};
                    uint2 v1 = {q1[0] | (q1[1] << 16), q1[2] | (q1[3] << 16)};
                    uint2 v2 = {q2[0] | (q2[1] << 16), q2[2] | (q2[3] << 16)};
                    *(uint2*)(rp)         = v0;
                    *(uint2*)(rp + 17408) = v1;
                    *(uint2*)(rp + 34816) = v2;
                }
            }
        }
        __syncthreads();   // B3: h2 planes ready

        // ---- GEMM3: waves 0..2, p-tile 16wv ----
        f32x4 acc3[4];
        #pragma unroll
        for (int st = 0; st < 4; ++st) acc3[st] = (f32x4){0.f, 0.f, 0.f, 0.f};
        if (wv < 3) {
            const short8* W3F8 = (const short8*)W3F;
            int qb = (l * 3 + wv) * 4;
            short8 Ac[3], An[3];
            #pragma unroll
            for (int p = 0; p < 3; ++p)
                Ac[p] = W3F8[((qb + 0) * 3 + p) * 64 + ln];
            #pragma unroll 1
            for (int cs = 0; cs < 4; ++cs) {
                if (cs < 3) {
                    #pragma unroll
                    for (int p = 0; p < 3; ++p)
                        An[p] = W3F8[((qb + cs + 1) * 3 + p) * 64 + ln];
                }
                #pragma unroll
                for (int st = 0; st < 4; ++st) {
                    int row = 16 * st + sm;
                    short8 b0 = plane_read(pl, 0, row, cs, qd);
                    short8 b1 = plane_read(pl, 1, row, cs, qd);
                    short8 bb = plane_read(pl, 2, row, cs, qd);
                    f32x4 a = acc3[st];
                    a = MFMA(Ac[0], b0, a, 0, 0, 0);
                    a = MFMA(Ac[0], b1, a, 0, 0, 0);
                    a = MFMA(Ac[1], b0, a, 0, 0, 0);
                    a = MFMA(Ac[0], bb, a, 0, 0, 0);
                    a = MFMA(Ac[1], b1, a, 0, 0, 0);
                    a = MFMA(Ac[2], b0, a, 0, 0, 0);
                    acc3[st] = a;
                }
                if (cs < 3) {
                    #pragma unroll
                    for (int i = 0; i < 3; ++i) Ac[i] = An[i];
                }
            }
        }
        __syncthreads();   // B4: all h2 reads done -> pbuf overlay safe

        if (wv < 3) {
            #pragma unroll
            for (int st = 0; st < 4; ++st)
                #pragma unroll
                for (int r = 0; r < 4; ++r)
                    pbuf[(16 * wv + 4 * qd + r) * 65 + 16 * st + sm] = acc3[st][r];
        }
        __syncthreads();   // B5: params visible

        // ---- spline: thread (f = tid>>6, s = tid&63) ----
        if (tid < 128) {
            int f = tid >> 6, s = tid & 63;
            const float* b3l = b3 + l * 46;
            float pr[23];
            #pragma unroll
            for (int i = 0; i < 23; ++i)
                pr[i] = pbuf[(2 * i + f) * 65 + s] + b3l[2 * i + f];

            float xin = xbuf[s][f == 0 ? ii0 : ii1];

            float d[9];
            d[0] = 1.f; d[8] = 1.f;
            #pragma unroll
            for (int k = 1; k < 8; ++k) d[k] = 1e-6f + softplus_f(pr[16 + k - 1]);

            bool inside = (xin >= -TAILB) && (xin <= TAILB);
            float xc = fminf(fmaxf(xin, -TAILB), TAILB);

            float mw = pr[0], mh = pr[8];
            #pragma unroll
            for (int k = 1; k < 8; ++k) { mw = fmaxf(mw, pr[k]); mh = fmaxf(mh, pr[8 + k]); }
            float ew[8], eh[8], swm = 0.f, shm = 0.f;
            #pragma unroll
            for (int k = 0; k < 8; ++k) {
                ew[k] = __expf(pr[k] - mw);     swm += ew[k];
                eh[k] = __expf(pr[8 + k] - mh); shm += eh[k];
            }
            const float c1 = 1.f - 8e-6f;
            float isw = c1 / swm, ish = c1 / shm;

            float cum_w = 0.f, cum_h = 0.f;
            float cwk = -TAILB, chk = -TAILB;
            float s_cw = -TAILB, s_w = 2.f * TAILB, s_ch = -TAILB, s_h = 2.f * TAILB;
            float s_d0 = 1.f, s_d1 = d[1];
            #pragma unroll
            for (int k = 0; k < 8; ++k) {
                cum_w += fmaf(ew[k], isw, 1e-6f);
                cum_h += fmaf(eh[k], ish, 1e-6f);
                float cwn = (k == 7) ? TAILB : fmaf(2.f * TAILB, cum_w, -TAILB);
                float chn = (k == 7) ? TAILB : fmaf(2.f * TAILB, cum_h, -TAILB);
                bool ge = (xc >= cwk);
                s_cw = ge ? cwk : s_cw;  s_w = ge ? (cwn - cwk) : s_w;
                s_ch = ge ? chk : s_ch;  s_h = ge ? (chn - chk) : s_h;
                s_d0 = ge ? d[k] : s_d0; s_d1 = ge ? d[k + 1] : s_d1;
                cwk = cwn; chk = chn;
            }

            float th    = (xc - s_cw) / s_w;
            float delta = s_h / s_w;
            float omt   = 1.f - th;
            float tomt  = th * omt;
            float num   = s_h * fmaf(delta, th * th, s_d0 * tomt);
            float den   = fmaf(s_d0 + s_d1 - 2.f * delta, tomt, delta);
            float y     = s_ch + num / den;
            float dnum  = delta * delta * (s_d1 * th * th + 2.f * delta * tomt + s_d0 * omt * omt);
            float lad   = __logf(dnum) - 2.f * __logf(den);

            xbuf[s][f == 0 ? ii0 : ii1] = inside ? y : xin;
            ladreg += inside ? lad : 0.f;
        }
        __syncthreads();   // B6: spline done; next phase1 may overwrite planes
    } // l

    if (tid < 128) ladb[tid] = ladreg;
    __syncthreads();
    if (tid < 64) {
        float4 xo;
        xo.x = xbuf[tid][0]; xo.y = xbuf[tid][1];
        xo.z = xbuf[tid][2]; xo.w = xbuf[tid][3];
        reinterpret_cast<float4*>(out)[base + tid] = xo;
        out[(size_t)B * 4 + base + tid] = ladb[tid] + ladb[tid + 64];
    }
}

extern "C" void kernel_launch(void* const* d_in, const int* in_sizes, int n_in,
                              void* d_out, int out_size, void* d_ws, size_t ws_size,
                              hipStream_t stream) {
    const float* inp  = (const float*)d_in[0];
    const float* cond = (const float*)d_in[1];
    const float* W1   = (const float*)d_in[2];
    const float* b1   = (const float*)d_in[3];
    const float* W2   = (const float*)d_in[4];
    const float* b2   = (const float*)d_in[5];
    const float* W3   = (const float*)d_in[6];
    const float* b3   = (const float*)d_in[7];
    float* out = (float*)d_out;
    int B = in_sizes[0] / 4;

    char* ws = (char*)d_ws;
    unsigned short* W2F = (unsigned short*)(ws);            // 393216 B
    unsigned short* W3F = (unsigned short*)(ws + 393216);   // 147456 B
    float4*         w1p = (float4*)(ws + 540672);           // 8192 B

    hipLaunchKernelGGL(prep_v9, dim3(354), dim3(256), 0, stream,
                       W1, b1, W2, W3, W2F, W3F, w1p);
    hipLaunchKernelGGL(rqs_v9, dim3(B / 64), dim3(256), 0, stream,
                       inp, cond, W2F, W3F, w1p, b2, b3, out, B);
}

// Round 10
// 338.242 us; speedup vs baseline: 3.4689x; 1.1482x over previous
//
#include <hip/hip_runtime.h>

#define TAILB 12.0f
#define INV2048 4.8828125e-4f

typedef _Float16 half8 __attribute__((ext_vector_type(8)));
typedef _Float16 half4 __attribute__((ext_vector_type(4)));
typedef __attribute__((ext_vector_type(4))) float f32x4;

#define MFMAH __builtin_amdgcn_mfma_f32_16x16x32_f16

__device__ __forceinline__ float softplus_f(float z) {
    return (z > 15.f) ? z : log1pf(__expf(z));
}

// fp16 2-term scaled split: v = h0 + h1/2048 + eps, |eps| <= 2^-22 |v|.
// Residual scaled x2048 BEFORE quantization -> stays in fp16 normal range.
__device__ __forceinline__ void split2h(float v, _Float16& o0, _Float16& o1) {
    _Float16 h0 = (_Float16)v;            // v_cvt_f16_f32 (RNE)
    float r1 = v - (float)h0;             // exact (Sterbenz)
    o0 = h0;
    o1 = (_Float16)(r1 * 2048.0f);        // exact scale, RNE quantize
}

// ---------------- prep: A-fragment-packed 2-plane fp16 weights ----------------
// W2F: tile = ((l*4+wv)*2+t)*4+cs; elem [(tile*2+p)*512 + ln*8 + j]
//      source W2[l][n=32wv+16t+(ln&15)][k=32cs+8(ln>>4)+j]      (262144 B)
// W3F: tile3 = (l*3+wv)*4+cs; elem [(tile3*2+p)*512 + ln*8 + j]
//      source W3[l][p=16wv+(ln&15)][n=32cs+8(ln>>4)+j], rows>=46 zero (98304 B)
// w1p: [l][k] = {W1[k][0..2], b1[k]}                            (8192 B)
__global__ __launch_bounds__(256)
void prep_v10(const float* __restrict__ W1, const float* __restrict__ b1,
              const float* __restrict__ W2, const float* __restrict__ W3,
              _Float16* __restrict__ W2F, _Float16* __restrict__ W3F,
              float4* __restrict__ w1p)
{
    int id = blockIdx.x * 256 + threadIdx.x;
    if (id < 65536) {
        int j = id & 7, ln = (id >> 3) & 63, tile = id >> 9;
        int cs = tile & 3, t = (tile >> 2) & 1, wv = (tile >> 3) & 3, l = tile >> 5;
        int n = 32 * wv + 16 * t + (ln & 15);
        int k = 32 * cs + 8 * (ln >> 4) + j;
        _Float16 a, b;
        split2h(W2[l * 16384 + n * 128 + k], a, b);
        W2F[(tile * 2 + 0) * 512 + ln * 8 + j] = a;
        W2F[(tile * 2 + 1) * 512 + ln * 8 + j] = b;
    } else if (id < 90112) {
        int t2 = id - 65536;
        int j = t2 & 7, ln = (t2 >> 3) & 63, tile3 = t2 >> 9;
        int cs = tile3 & 3, q = tile3 >> 2;
        int wv = q % 3, l = q / 3;
        int p = 16 * wv + (ln & 15);
        int n = 32 * cs + 8 * (ln >> 4) + j;
        float v = (p < 46) ? W3[l * 5888 + p * 128 + n] : 0.f;
        _Float16 a, b;
        split2h(v, a, b);
        W3F[(tile3 * 2 + 0) * 512 + ln * 8 + j] = a;
        W3F[(tile3 * 2 + 1) * 512 + ln * 8 + j] = b;
    } else if (id < 90624) {
        int t = id - 90112;
        int l = t >> 7, k = t & 127;
        float4 v;
        v.x = W1[l * 384 + k * 3 + 0];
        v.y = W1[l * 384 + k * 3 + 1];
        v.z = W1[l * 384 + k * 3 + 2];
        v.w = b1[l * 128 + k];
        w1p[t] = v;
    }
}

// Activation planes: 2 x 64 rows x 136 fp16 (272 B rows). 16B-group pg stored
// at (pg ^ ((row>>3)&7))*16  (v9 scheme, 2/3 the traffic).
__device__ __forceinline__ half8 plane_read(const char* pl, int p, int row,
                                            int cs, int qd) {
    int pg = 4 * cs + qd;
    int key = (row >> 3) & 7;
    return *reinterpret_cast<const half8*>(pl + p * 17408 + row * 272 + ((pg ^ key) << 4));
}

// 64 samples/block, 4 waves. Wave wv: n in [32wv,+32) (GEMM2), p-tile 16wv
// (GEMM3, wv<3). GEMM = A + B/2048 with A=S w0b0, B=S(w0b1'+w1'b0): 3 MFMA
// per k-chunk (vs 6 in v9), rel err ~2e-7 < existing fast-math noise.
__global__ __launch_bounds__(256, 3)
void rqs_v10(const float* __restrict__ inp, const float* __restrict__ cond,
             const _Float16* __restrict__ W2F, const _Float16* __restrict__ W3F,
             const float4* __restrict__ w1p,
             const float* __restrict__ b2, const float* __restrict__ b3,
             float* __restrict__ out, int B)
{
    __shared__ __align__(16) _Float16 planes[2][64][136];   // 34816 B; pbuf overlays
    __shared__ float xbuf[64][5];

    float* pbuf = (float*)planes;            // [48][65] = 12480 B
    float* ladb = pbuf + 3120;               // [2][64] (overlay, used at end)
    const char* pl = (const char*)&planes[0][0][0];

    const int tid  = threadIdx.x;
    const int base = blockIdx.x * 64;
    const int wv   = tid >> 6;
    const int ln   = tid & 63;
    const int sm   = ln & 15;
    const int qd   = ln >> 4;

    if (tid < 64) {
        float4 xi = reinterpret_cast<const float4*>(inp)[base + tid];
        xbuf[tid][0] = xi.x; xbuf[tid][1] = xi.y;
        xbuf[tid][2] = xi.z; xbuf[tid][3] = xi.w;
        xbuf[tid][4] = cond[base + tid];
    }
    float ladreg = 0.f;
    __syncthreads();

    #pragma unroll 1
    for (int l = 0; l < 4; ++l) {
        int mi0, mi1, ii0, ii1;
        switch (l) {
            case 0:  mi0 = 0; mi1 = 2; ii0 = 1; ii1 = 3; break;
            case 1:  mi0 = 1; mi1 = 3; ii0 = 0; ii1 = 2; break;
            case 2:  mi0 = 0; mi1 = 1; ii0 = 2; ii1 = 3; break;
            default: mi0 = 2; mi1 = 3; ii0 = 0; ii1 = 1; break;
        }

        // ---- phase 1: h1 planes; wave wv covers k in [32wv,+32) for 64 samples ----
        {
            int s = tid & 63;
            float m0 = xbuf[s][mi0], m1 = xbuf[s][mi1], cc = xbuf[s][4];
            const float4* w1l = w1p + l * 128;
            int key = (s >> 3) & 7;
            char* rowp = (char*)pl + s * 272;
            #pragma unroll
            for (int g = 0; g < 8; ++g) {
                int k0 = 32 * wv + 4 * g;                  // wave-uniform -> s_loads
                half4 v0, v1;
                #pragma unroll
                for (int r = 0; r < 4; ++r) {
                    float4 w4 = w1l[k0 + r];
                    float v = fmaf(w4.x, m0, fmaf(w4.y, m1, fmaf(w4.z, cc, w4.w)));
                    v = fmaxf(v, 0.f);
                    _Float16 a, b;
                    split2h(v, a, b);
                    v0[r] = a; v1[r] = b;
                }
                int pg = 4 * wv + (g >> 1);
                int boff = ((pg ^ key) << 4) + ((g & 1) << 3);
                *(half4*)(rowp + boff)         = v0;
                *(half4*)(rowp + boff + 17408) = v1;
            }
        }
        __syncthreads();   // B1: h1 planes ready

        // ---- GEMM2: wave wv -> h2 rows [32wv,+32) x 64 samples; 3 MFMA/chunk ----
        f32x4 accA[2][4], accB[2][4];
        #pragma unroll
        for (int t = 0; t < 2; ++t)
            #pragma unroll
            for (int st = 0; st < 4; ++st) {
                accA[t][st] = (f32x4){0.f, 0.f, 0.f, 0.f};
                accB[t][st] = (f32x4){0.f, 0.f, 0.f, 0.f};
            }
        {
            const half8* W2F8 = (const half8*)W2F;
            int tb = (l * 4 + wv) * 2;
            half8 Ac[4], An[4];        // [tile t][plane p]
            #pragma unroll
            for (int t = 0; t < 2; ++t)
                #pragma unroll
                for (int p = 0; p < 2; ++p)
                    Ac[t * 2 + p] = W2F8[(((tb + t) * 4 + 0) * 2 + p) * 64 + ln];
            #pragma unroll 1
            for (int cs = 0; cs < 4; ++cs) {
                if (cs < 3) {
                    #pragma unroll
                    for (int t = 0; t < 2; ++t)
                        #pragma unroll
                        for (int p = 0; p < 2; ++p)
                            An[t * 2 + p] = W2F8[(((tb + t) * 4 + cs + 1) * 2 + p) * 64 + ln];
                }
                #pragma unroll
                for (int st = 0; st < 4; ++st) {
                    int row = 16 * st + sm;
                    half8 b0 = plane_read(pl, 0, row, cs, qd);
                    half8 b1 = plane_read(pl, 1, row, cs, qd);
                    #pragma unroll
                    for (int t = 0; t < 2; ++t) {
                        accA[t][st] = MFMAH(Ac[t * 2 + 0], b0, accA[t][st], 0, 0, 0);
                        accB[t][st] = MFMAH(Ac[t * 2 + 0], b1, accB[t][st], 0, 0, 0);
                        accB[t][st] = MFMAH(Ac[t * 2 + 1], b0, accB[t][st], 0, 0, 0);
                    }
                }
                if (cs < 3) {
                    #pragma unroll
                    for (int i = 0; i < 4; ++i) Ac[i] = An[i];
                }
            }
        }
        __syncthreads();   // B2: all h1 reads done -> h2 overwrite safe

        // ---- h2 epilogue: combine A + B/2048, bias+relu, split, write planes ----
        {
            const float* b2l = b2 + l * 128;
            #pragma unroll
            for (int t = 0; t < 2; ++t) {
                float4 bias = *(const float4*)(b2l + 32 * wv + 16 * t + 4 * qd);
                float bb[4] = {bias.x, bias.y, bias.z, bias.w};
                #pragma unroll
                for (int st = 0; st < 4; ++st) {
                    half4 v0, v1;
                    #pragma unroll
                    for (int r = 0; r < 4; ++r) {
                        float hv = fmaf(INV2048, accB[t][st][r], accA[t][st][r]) + bb[r];
                        hv = fmaxf(hv, 0.f);
                        _Float16 a, b;
                        split2h(hv, a, b);
                        v0[r] = a; v1[r] = b;
                    }
                    int row = 16 * st + sm;
                    int key = (row >> 3) & 7;
                    int pg = 4 * wv + 2 * t + (qd >> 1);
                    int boff = ((pg ^ key) << 4) + ((qd & 1) << 3);
                    char* rp = (char*)pl + row * 272 + boff;
                    *(half4*)(rp)         = v0;
                    *(half4*)(rp + 17408) = v1;
                }
            }
        }
        __syncthreads();   // B3: h2 planes ready

        // ---- GEMM3: waves 0..2, p-tile 16wv ----
        f32x4 acc3A[4], acc3B[4];
        #pragma unroll
        for (int st = 0; st < 4; ++st) {
            acc3A[st] = (f32x4){0.f, 0.f, 0.f, 0.f};
            acc3B[st] = (f32x4){0.f, 0.f, 0.f, 0.f};
        }
        if (wv < 3) {
            const half8* W3F8 = (const half8*)W3F;
            int qb = (l * 3 + wv) * 4;
            half8 Ac[2], An[2];
            #pragma unroll
            for (int p = 0; p < 2; ++p)
                Ac[p] = W3F8[((qb + 0) * 2 + p) * 64 + ln];
            #pragma unroll 1
            for (int cs = 0; cs < 4; ++cs) {
                if (cs < 3) {
                    #pragma unroll
                    for (int p = 0; p < 2; ++p)
                        An[p] = W3F8[((qb + cs + 1) * 2 + p) * 64 + ln];
                }
                #pragma unroll
                for (int st = 0; st < 4; ++st) {
                    int row = 16 * st + sm;
                    half8 b0 = plane_read(pl, 0, row, cs, qd);
                    half8 b1 = plane_read(pl, 1, row, cs, qd);
                    acc3A[st] = MFMAH(Ac[0], b0, acc3A[st], 0, 0, 0);
                    acc3B[st] = MFMAH(Ac[0], b1, acc3B[st], 0, 0, 0);
                    acc3B[st] = MFMAH(Ac[1], b0, acc3B[st], 0, 0, 0);
                }
                if (cs < 3) {
                    Ac[0] = An[0]; Ac[1] = An[1];
                }
            }
        }
        __syncthreads();   // B4: all h2 reads done -> pbuf overlay safe

        if (wv < 3) {
            #pragma unroll
            for (int st = 0; st < 4; ++st)
                #pragma unroll
                for (int r = 0; r < 4; ++r)
                    pbuf[(16 * wv + 4 * qd + r) * 65 + 16 * st + sm] =
                        fmaf(INV2048, acc3B[st][r], acc3A[st][r]);
        }
        __syncthreads();   // B5: params visible

        // ---- spline: thread (f = tid>>6, s = tid&63) ----
        if (tid < 128) {
            int f = tid >> 6, s = tid & 63;
            const float* b3l = b3 + l * 46;
            float pr[23];
            #pragma unroll
            for (int i = 0; i < 23; ++i)
                pr[i] = pbuf[(2 * i + f) * 65 + s] + b3l[2 * i + f];

            float xin = xbuf[s][f == 0 ? ii0 : ii1];

            float d[9];
            d[0] = 1.f; d[8] = 1.f;
            #pragma unroll
            for (int k = 1; k < 8; ++k) d[k] = 1e-6f + softplus_f(pr[16 + k - 1]);

            bool inside = (xin >= -TAILB) && (xin <= TAILB);
            float xc = fminf(fmaxf(xin, -TAILB), TAILB);

            float mw = pr[0], mh = pr[8];
            #pragma unroll
            for (int k = 1; k < 8; ++k) { mw = fmaxf(mw, pr[k]); mh = fmaxf(mh, pr[8 + k]); }
            float ew[8], eh[8], swm = 0.f, shm = 0.f;
            #pragma unroll
            for (int k = 0; k < 8; ++k) {
                ew[k] = __expf(pr[k] - mw);     swm += ew[k];
                eh[k] = __expf(pr[8 + k] - mh); shm += eh[k];
            }
            const float c1 = 1.f - 8e-6f;
            float isw = c1 / swm, ish = c1 / shm;

            float cum_w = 0.f, cum_h = 0.f;
            float cwk = -TAILB, chk = -TAILB;
            float s_cw = -TAILB, s_w = 2.f * TAILB, s_ch = -TAILB, s_h = 2.f * TAILB;
            float s_d0 = 1.f, s_d1 = d[1];
            #pragma unroll
            for (int k = 0; k < 8; ++k) {
                cum_w += fmaf(ew[k], isw, 1e-6f);
                cum_h += fmaf(eh[k], ish, 1e-6f);
                float cwn = (k == 7) ? TAILB : fmaf(2.f * TAILB, cum_w, -TAILB);
                float chn = (k == 7) ? TAILB : fmaf(2.f * TAILB, cum_h, -TAILB);
                bool ge = (xc >= cwk);
                s_cw = ge ? cwk : s_cw;  s_w = ge ? (cwn - cwk) : s_w;
                s_ch = ge ? chk : s_ch;  s_h = ge ? (chn - chk) : s_h;
                s_d0 = ge ? d[k] : s_d0; s_d1 = ge ? d[k + 1] : s_d1;
                cwk = cwn; chk = chn;
            }

            float th    = (xc - s_cw) / s_w;
            float delta = s_h / s_w;
            float omt   = 1.f - th;
            float tomt  = th * omt;
            float num   = s_h * fmaf(delta, th * th, s_d0 * tomt);
            float den   = fmaf(s_d0 + s_d1 - 2.f * delta, tomt, delta);
            float y     = s_ch + num / den;
            float dnum  = delta * delta * (s_d1 * th * th + 2.f * delta * tomt + s_d0 * omt * omt);
            float lad   = __logf(dnum) - 2.f * __logf(den);

            xbuf[s][f == 0 ? ii0 : ii1] = inside ? y : xin;
            ladreg += inside ? lad : 0.f;
        }
        __syncthreads();   // B6: spline done; next phase1 may overwrite planes
    } // l

    if (tid < 128) ladb[tid] = ladreg;
    __syncthreads();
    if (tid < 64) {
        float4 xo;
        xo.x = xbuf[tid][0]; xo.y = xbuf[tid][1];
        xo.z = xbuf[tid][2]; xo.w = xbuf[tid][3];
        reinterpret_cast<float4*>(out)[base + tid] = xo;
        out[(size_t)B * 4 + base + tid] = ladb[tid] + ladb[tid + 64];
    }
}

extern "C" void kernel_launch(void* const* d_in, const int* in_sizes, int n_in,
                              void* d_out, int out_size, void* d_ws, size_t ws_size,
                              hipStream_t stream) {
    const float* inp  = (const float*)d_in[0];
    const float* cond = (const float*)d_in[1];
    const float* W1   = (const float*)d_in[2];
    const float* b1   = (const float*)d_in[3];
    const float* W2   = (const float*)d_in[4];
    const float* b2   = (const float*)d_in[5];
    const float* W3   = (const float*)d_in[6];
    const float* b3   = (const float*)d_in[7];
    float* out = (float*)d_out;
    int B = in_sizes[0] / 4;

    char* ws = (char*)d_ws;
    _Float16* W2F = (_Float16*)(ws);            // 262144 B
    _Float16* W3F = (_Float16*)(ws + 262144);   // 98304 B
    float4*   w1p = (float4*)(ws + 360448);     // 8192 B

    hipLaunchKernelGGL(prep_v10, dim3(354), dim3(256), 0, stream,
                       W1, b1, W2, W3, W2F, W3F, w1p);
    hipLaunchKernelGGL(rqs_v10, dim3(B / 64), dim3(256), 0, stream,
                       inp, cond, W2F, W3F, w1p, b2, b3, out, B);
}

// Round 12
// 306.424 us; speedup vs baseline: 3.8291x; 1.1038x over previous
//
#include <hip/hip_runtime.h>

#define TAILB 12.0f
#define INV2048 4.8828125e-4f

typedef _Float16 half8 __attribute__((ext_vector_type(8)));
typedef _Float16 half4 __attribute__((ext_vector_type(4)));
typedef __fp16 fp16x2 __attribute__((ext_vector_type(2)));   // pkrtz return type
typedef __attribute__((ext_vector_type(4))) float f32x4;

#define MFMAH __builtin_amdgcn_mfma_f32_16x16x32_f16

__device__ __forceinline__ float softplus_f(float z) {
    return (z > 15.f) ? z : log1pf(__expf(z));
}

// fp16 2-term scaled split (RNE, prep only)
__device__ __forceinline__ void split2h(float v, _Float16& o0, _Float16& o1) {
    _Float16 h0 = (_Float16)v;
    float r1 = v - (float)h0;
    o0 = h0;
    o1 = (_Float16)(r1 * 2048.0f);
}

// pkrtz-based split of 4 values -> two packed half4 planes (RTZ both terms;
// per-factor err <= 2^-22 |v|, same order as RNE split — absmax margin absorbs it)
__device__ __forceinline__ void split4_pk(const float v[4], half4& p0, half4& p1) {
    fp16x2 lo = __builtin_amdgcn_cvt_pkrtz(v[0], v[1]);
    fp16x2 hi = __builtin_amdgcn_cvt_pkrtz(v[2], v[3]);
    float r0 = (v[0] - (float)lo.x) * 2048.f;
    float r1 = (v[1] - (float)lo.y) * 2048.f;
    float r2 = (v[2] - (float)hi.x) * 2048.f;
    float r3 = (v[3] - (float)hi.y) * 2048.f;
    fp16x2 rlo = __builtin_amdgcn_cvt_pkrtz(r0, r1);
    fp16x2 rhi = __builtin_amdgcn_cvt_pkrtz(r2, r3);
    p0 = (half4){(_Float16)lo.x, (_Float16)lo.y, (_Float16)hi.x, (_Float16)hi.y};
    p1 = (half4){(_Float16)rlo.x, (_Float16)rlo.y, (_Float16)rhi.x, (_Float16)rhi.y};
}

// ---------------- prep: identical layout to v10 ----------------
__global__ __launch_bounds__(256)
void prep_v11(const float* __restrict__ W1, const float* __restrict__ b1,
              const float* __restrict__ W2, const float* __restrict__ W3,
              _Float16* __restrict__ W2F, _Float16* __restrict__ W3F,
              float4* __restrict__ w1p)
{
    int id = blockIdx.x * 256 + threadIdx.x;
    if (id < 65536) {
        int j = id & 7, ln = (id >> 3) & 63, tile = id >> 9;
        int cs = tile & 3, t = (tile >> 2) & 1, wv = (tile >> 3) & 3, l = tile >> 5;
        int n = 32 * wv + 16 * t + (ln & 15);
        int k = 32 * cs + 8 * (ln >> 4) + j;
        _Float16 a, b;
        split2h(W2[l * 16384 + n * 128 + k], a, b);
        W2F[(tile * 2 + 0) * 512 + ln * 8 + j] = a;
        W2F[(tile * 2 + 1) * 512 + ln * 8 + j] = b;
    } else if (id < 90112) {
        int t2 = id - 65536;
        int j = t2 & 7, ln = (t2 >> 3) & 63, tile3 = t2 >> 9;
        int cs = tile3 & 3, q = tile3 >> 2;
        int wv = q % 3, l = q / 3;
        int p = 16 * wv + (ln & 15);
        int n = 32 * cs + 8 * (ln >> 4) + j;
        float v = (p < 46) ? W3[l * 5888 + p * 128 + n] : 0.f;
        _Float16 a, b;
        split2h(v, a, b);
        W3F[(tile3 * 2 + 0) * 512 + ln * 8 + j] = a;
        W3F[(tile3 * 2 + 1) * 512 + ln * 8 + j] = b;
    } else if (id < 90624) {
        int t = id - 90112;
        int l = t >> 7, k = t & 127;
        float4 v;
        v.x = W1[l * 384 + k * 3 + 0];
        v.y = W1[l * 384 + k * 3 + 1];
        v.z = W1[l * 384 + k * 3 + 2];
        v.w = b1[l * 128 + k];
        w1p[t] = v;
    }
}

// 64 samples/block, 4 waves. Same math as v10 (A + B/2048 split-fp16 MFMA,
// absmax-verified). Changes: pkrtz packed conversions, layer-invariant LDS
// addresses precomputed once (plane-1 as +17408 immediate), cs loops fully
// unrolled, pbuf transposed [64][52] for b128 epilogue writes / spline reads.
__global__ __launch_bounds__(256, 3)
void rqs_v11(const float* __restrict__ inp, const float* __restrict__ cond,
             const _Float16* __restrict__ W2F, const _Float16* __restrict__ W3F,
             const float4* __restrict__ w1p,
             const float* __restrict__ b2, const float* __restrict__ b3,
             float* __restrict__ out, int B)
{
    __shared__ __align__(16) _Float16 planes[2][64][136];   // 34816 B; pbuf overlays
    __shared__ float xbuf[64][5];

    char* plw = (char*)&planes[0][0][0];
    const char* pl = plw;
    float* ladb = (float*)(plw + 13312);       // [128] overlay, used after last barrier

    const int tid  = threadIdx.x;
    const int base = blockIdx.x * 64;
    const int wv   = tid >> 6;
    const int ln   = tid & 63;
    const int sm   = ln & 15;
    const int qd   = ln >> 4;
    const int s1   = tid & 63;                 // phase-1 sample

    // ---- layer-invariant LDS addresses (held in VGPRs) ----
    int rdaddr[4][4];                          // plane reads [st][cs]
    #pragma unroll
    for (int st = 0; st < 4; ++st) {
        int row = 16 * st + sm, key = (row >> 3) & 7;
        #pragma unroll
        for (int cs = 0; cs < 4; ++cs)
            rdaddr[st][cs] = row * 272 + (((4 * cs + qd) ^ key) << 4);
    }
    int wra[8];                                // phase-1 writes [g]
    {
        int key = (s1 >> 3) & 7;
        #pragma unroll
        for (int g = 0; g < 8; ++g)
            wra[g] = s1 * 272 + (((4 * wv + (g >> 1)) ^ key) << 4) + ((g & 1) << 3);
    }
    int ewa[2][4];                             // h2 epilogue writes [t][st]
    #pragma unroll
    for (int t = 0; t < 2; ++t)
        #pragma unroll
        for (int st = 0; st < 4; ++st) {
            int row = 16 * st + sm, key = (row >> 3) & 7;
            int pg = 4 * wv + 2 * t + (qd >> 1);
            ewa[t][st] = row * 272 + ((pg ^ key) << 4) + ((qd & 1) << 3);
        }
    int pwa[4];                                // pbuf b128 writes [st]
    #pragma unroll
    for (int st = 0; st < 4; ++st)
        pwa[st] = (16 * st + sm) * 208 + (16 * wv + 4 * qd) * 4;

    if (tid < 64) {
        float4 xi = reinterpret_cast<const float4*>(inp)[base + tid];
        xbuf[tid][0] = xi.x; xbuf[tid][1] = xi.y;
        xbuf[tid][2] = xi.z; xbuf[tid][3] = xi.w;
        xbuf[tid][4] = cond[base + tid];
    }
    float ladreg = 0.f;
    __syncthreads();

    #pragma unroll 1
    for (int l = 0; l < 4; ++l) {
        int mi0, mi1, ii0, ii1;
        switch (l) {
            case 0:  mi0 = 0; mi1 = 2; ii0 = 1; ii1 = 3; break;
            case 1:  mi0 = 1; mi1 = 3; ii0 = 0; ii1 = 2; break;
            case 2:  mi0 = 0; mi1 = 1; ii0 = 2; ii1 = 3; break;
            default: mi0 = 2; mi1 = 3; ii0 = 0; ii1 = 1; break;
        }

        // ---- phase 1: h1 planes (wave wv covers k in [32wv,+32) for its sample) ----
        {
            float m0 = xbuf[s1][mi0], m1 = xbuf[s1][mi1], cc = xbuf[s1][4];
            const float4* w1l = w1p + l * 128;
            #pragma unroll
            for (int g = 0; g < 8; ++g) {
                int k0 = 32 * wv + 4 * g;
                float v[4];
                #pragma unroll
                for (int r = 0; r < 4; ++r) {
                    float4 w4 = w1l[k0 + r];
                    v[r] = fmaxf(fmaf(w4.x, m0, fmaf(w4.y, m1, fmaf(w4.z, cc, w4.w))), 0.f);
                }
                half4 p0, p1;
                split4_pk(v, p0, p1);
                char* wp = plw + wra[g];
                *(half4*)(wp)          = p0;
                *(half4*)(wp + 17408)  = p1;
            }
        }
        __syncthreads();   // B1: h1 planes ready

        // ---- GEMM2: wave wv -> h2 rows [32wv,+32); bias-in-init; cs unrolled ----
        f32x4 accA[2][4], accB[2][4];
        {
            int nb = __builtin_amdgcn_readfirstlane(l * 128 + 32 * wv);
            #pragma unroll
            for (int t = 0; t < 2; ++t) {
                float4 bias = *(const float4*)(b2 + nb + 16 * t + 4 * qd);
                #pragma unroll
                for (int st = 0; st < 4; ++st) {
                    accA[t][st] = (f32x4){bias.x, bias.y, bias.z, bias.w};
                    accB[t][st] = (f32x4){0.f, 0.f, 0.f, 0.f};
                }
            }
            const half8* W2F8 = (const half8*)W2F;
            int tb = (l * 4 + wv) * 2;
            #pragma unroll
            for (int cs = 0; cs < 4; ++cs) {
                half8 A00 = W2F8[(((tb + 0) * 4 + cs) * 2 + 0) * 64 + ln];
                half8 A01 = W2F8[(((tb + 0) * 4 + cs) * 2 + 1) * 64 + ln];
                half8 A10 = W2F8[(((tb + 1) * 4 + cs) * 2 + 0) * 64 + ln];
                half8 A11 = W2F8[(((tb + 1) * 4 + cs) * 2 + 1) * 64 + ln];
                #pragma unroll
                for (int st = 0; st < 4; ++st) {
                    half8 b0 = *(const half8*)(pl + rdaddr[st][cs]);
                    half8 b1 = *(const half8*)(pl + rdaddr[st][cs] + 17408);
                    accA[0][st] = MFMAH(A00, b0, accA[0][st], 0, 0, 0);
                    accB[0][st] = MFMAH(A00, b1, accB[0][st], 0, 0, 0);
                    accB[0][st] = MFMAH(A01, b0, accB[0][st], 0, 0, 0);
                    accA[1][st] = MFMAH(A10, b0, accA[1][st], 0, 0, 0);
                    accB[1][st] = MFMAH(A10, b1, accB[1][st], 0, 0, 0);
                    accB[1][st] = MFMAH(A11, b0, accB[1][st], 0, 0, 0);
                }
            }
        }
        __syncthreads();   // B2: all h1 reads done -> h2 overwrite safe

        // ---- h2 epilogue: combine, relu, pkrtz split, write planes ----
        {
            #pragma unroll
            for (int t = 0; t < 2; ++t) {
                #pragma unroll
                for (int st = 0; st < 4; ++st) {
                    float v[4];
                    #pragma unroll
                    for (int r = 0; r < 4; ++r)
                        v[r] = fmaxf(fmaf(INV2048, accB[t][st][r], accA[t][st][r]), 0.f);
                    half4 p0, p1;
                    split4_pk(v, p0, p1);
                    char* wp = plw + ewa[t][st];
                    *(half4*)(wp)         = p0;
                    *(half4*)(wp + 17408) = p1;
                }
            }
        }
        __syncthreads();   // B3: h2 planes ready

        // ---- GEMM3: waves 0..2, p-tile 16wv; cs unrolled ----
        f32x4 acc3A[4], acc3B[4];
        #pragma unroll
        for (int st = 0; st < 4; ++st) {
            acc3A[st] = (f32x4){0.f, 0.f, 0.f, 0.f};
            acc3B[st] = (f32x4){0.f, 0.f, 0.f, 0.f};
        }
        if (wv < 3) {
            const half8* W3F8 = (const half8*)W3F;
            int qb = (l * 3 + wv) * 4;
            #pragma unroll
            for (int cs = 0; cs < 4; ++cs) {
                half8 A0 = W3F8[((qb + cs) * 2 + 0) * 64 + ln];
                half8 A1 = W3F8[((qb + cs) * 2 + 1) * 64 + ln];
                #pragma unroll
                for (int st = 0; st < 4; ++st) {
                    half8 b0 = *(const half8*)(pl + rdaddr[st][cs]);
                    half8 b1 = *(const half8*)(pl + rdaddr[st][cs] + 17408);
                    acc3A[st] = MFMAH(A0, b0, acc3A[st], 0, 0, 0);
                    acc3B[st] = MFMAH(A0, b1, acc3B[st], 0, 0, 0);
                    acc3B[st] = MFMAH(A1, b0, acc3B[st], 0, 0, 0);
                }
            }
        }
        __syncthreads();   // B4: all h2 reads done -> pbuf overlay safe

        if (wv < 3) {
            #pragma unroll
            for (int st = 0; st < 4; ++st) {
                float4 pv;
                pv.x = fmaf(INV2048, acc3B[st][0], acc3A[st][0]);
                pv.y = fmaf(INV2048, acc3B[st][1], acc3A[st][1]);
                pv.z = fmaf(INV2048, acc3B[st][2], acc3A[st][2]);
                pv.w = fmaf(INV2048, acc3B[st][3], acc3A[st][3]);
                *(float4*)(plw + pwa[st]) = pv;   // pbuf[row][16wv+4qd .. +3]
            }
        }
        __syncthreads();   // B5: params visible

        // ---- spline: thread (f = tid>>6, s = tid&63); pbuf row-major b128 reads ----
        if (tid < 128) {
            int f = tid >> 6, s = tid & 63;
            const float* b3l = b3 + l * 46;
            const float4* prow = (const float4*)(pl + s * 208);
            float pr[23];
            #pragma unroll
            for (int i = 0; i < 12; ++i) {
                float4 q = prow[i];                     // p = 4i .. 4i+3
                pr[2 * i] = (f ? q.y : q.x) + b3l[4 * i + f];
                if (2 * i + 1 < 23)
                    pr[2 * i + 1] = (f ? q.w : q.z) + b3l[4 * i + 2 + f];
            }

            float xin = xbuf[s][f == 0 ? ii0 : ii1];

            float d[9];
            d[0] = 1.f; d[8] = 1.f;
            #pragma unroll
            for (int k = 1; k < 8; ++k) d[k] = 1e-6f + softplus_f(pr[16 + k - 1]);

            bool inside = (xin >= -TAILB) && (xin <= TAILB);
            float xc = fminf(fmaxf(xin, -TAILB), TAILB);

            float mw = pr[0], mh = pr[8];
            #pragma unroll
            for (int k = 1; k < 8; ++k) { mw = fmaxf(mw, pr[k]); mh = fmaxf(mh, pr[8 + k]); }
            float ew[8], eh[8], swm = 0.f, shm = 0.f;
            #pragma unroll
            for (int k = 0; k < 8; ++k) {
                ew[k] = __expf(pr[k] - mw);     swm += ew[k];
                eh[k] = __expf(pr[8 + k] - mh); shm += eh[k];
            }
            const float c1 = 1.f - 8e-6f;
            float isw = c1 / swm, ish = c1 / shm;

            float cum_w = 0.f, cum_h = 0.f;
            float cwk = -TAILB, chk = -TAILB;
            float s_cw = -TAILB, s_w = 2.f * TAILB, s_ch = -TAILB, s_h = 2.f * TAILB;
            float s_d0 = 1.f, s_d1 = d[1];
            #pragma unroll
            for (int k = 0; k < 8; ++k) {
                cum_w += fmaf(ew[k], isw, 1e-6f);
                cum_h += fmaf(eh[k], ish, 1e-6f);
                float cwn = (k == 7) ? TAILB : fmaf(2.f * TAILB, cum_w, -TAILB);
                float chn = (k == 7) ? TAILB : fmaf(2.f * TAILB, cum_h, -TAILB);
                bool ge = (xc >= cwk);
                s_cw = ge ? cwk : s_cw;  s_w = ge ? (cwn - cwk) : s_w;
                s_ch = ge ? chk : s_ch;  s_h = ge ? (chn - chk) : s_h;
                s_d0 = ge ? d[k] : s_d0; s_d1 = ge ? d[k + 1] : s_d1;
                cwk = cwn; chk = chn;
            }

            float th    = (xc - s_cw) / s_w;
            float delta = s_h / s_w;
            float omt   = 1.f - th;
            float tomt  = th * omt;
            float num   = s_h * fmaf(delta, th * th, s_d0 * tomt);
            float den   = fmaf(s_d0 + s_d1 - 2.f * delta, tomt, delta);
            float y     = s_ch + num / den;
            float dnum  = delta * delta * (s_d1 * th * th + 2.f * delta * tomt + s_d0 * omt * omt);
            float lad   = __logf(dnum) - 2.f * __logf(den);

            xbuf[s][f == 0 ? ii0 : ii1] = inside ? y : xin;
            ladreg += inside ? lad : 0.f;
        }
        __syncthreads();   // B6: spline done; next phase1 may overwrite planes
    } // l

    if (tid < 128) ladb[tid] = ladreg;
    __syncthreads();
    if (tid < 64) {
        float4 xo;
        xo.x = xbuf[tid][0]; xo.y = xbuf[tid][1];
        xo.z = xbuf[tid][2]; xo.w = xbuf[tid][3];
        reinterpret_cast<float4*>(out)[base + tid] = xo;
        out[(size_t)B * 4 + base + tid] = ladb[tid] + ladb[tid + 64];
    }
}

extern "C" void kernel_launch(void* const* d_in, const int* in_sizes, int n_in,
                              void* d_out, int out_size, void* d_ws, size_t ws_size,
                              hipStream_t stream) {
    const float* inp  = (const float*)d_in[0];
    const float* cond = (const float*)d_in[1];
    const float* W1   = (const float*)d_in[2];
    const float* b1   = (const float*)d_in[3];
    const float* W2   = (const float*)d_in[4];
    const float* b2   = (const float*)d_in[5];
    const float* W3   = (const float*)d_in[6];
    const float* b3   = (const float*)d_in[7];
    float* out = (float*)d_out;
    int B = in_sizes[0] / 4;

    char* ws = (char*)d_ws;
    _Float16* W2F = (_Float16*)(ws);            // 262144 B
    _Float16* W3F = (_Float16*)(ws + 262144);   // 98304 B
    float4*   w1p = (float4*)(ws + 360448);     // 8192 B

    hipLaunchKernelGGL(prep_v11, dim3(354), dim3(256), 0, stream,
                       W1, b1, W2, W3, W2F, W3F, w1p);
    hipLaunchKernelGGL(rqs_v11, dim3(B / 64), dim3(256), 0, stream,
                       inp, cond, W2F, W3F, w1p, b2, b3, out, B);
}